// Round 8
// baseline (174.711 us; speedup 1.0000x reference)
//
#include <hip/hip_runtime.h>

// SingleVQC via MFMA: each VQC block = RY(x) state build (real tensor product)
// followed by a FIXED 256x256 complex unitary U_v (depends only on theta) and
// Z-expvals. U_v is prebuilt (bf16); main kernel: fused s-build -> bf16 GEMM
// (re,im) -> |Y|^2 -> signed reductions -> sin/cos, x4 VQCs.
//
// R8 vs R7 (103us steady): R7's __launch_bounds__(512,4) forced regs<=128
// total; with 64 AGPR acc that left ~64 VGPR -> zero load-prefetch -> each
// ks-step exposed ~250cy L2 latency. Now: __launch_bounds__(512,3) (~170 reg
// cap) + explicit rolling 1-ks-ahead B-prefetch in named registers.

typedef __attribute__((ext_vector_type(8))) short  bf16x8;
typedef __attribute__((ext_vector_type(4))) float  f32x4;

__device__ __forceinline__ ushort f2bf(float f) {
    unsigned u = __builtin_bit_cast(unsigned, f);
    u += 0x7fffu + ((u >> 16) & 1u);          // RNE
    return (ushort)(u >> 16);
}
__device__ __forceinline__ unsigned pack2(float a, float b) {
    return ((unsigned)f2bf(b) << 16) | (unsigned)f2bf(a);
}

// ---------------- gate-table prologue (unchanged, verified) ---------------
__global__ void gate_table_k(const float* __restrict__ theta,
                             float* __restrict__ gt) {
    int idx = blockIdx.x * blockDim.x + threadIdx.x;
    if (idx >= 128) return;
    float phi = theta[idx * 3 + 0];
    float th  = theta[idx * 3 + 1];
    float om  = theta[idx * 3 + 2];
    float ct = __cosf(0.5f * th),         st = __sinf(0.5f * th);
    float ca = __cosf(0.5f * (phi - om)), sa = __sinf(0.5f * (phi - om));
    float cb = __cosf(0.5f * (phi + om)), sb = __sinf(0.5f * (phi + om));
    float* g = gt + idx * 8;
    g[0] =  cb * ct;  g[1] = -sb * ct;
    g[2] = -ca * st;  g[3] = -sa * st;
    g[4] =  ca * st;  g[5] = -sa * st;
    g[6] =  cb * ct;  g[7] =  sb * ct;
}

// ---------------- U-build: one wave per (vqc, basis column) ---------------
// Computes column j of U_v (thread holds U[col=lane*4+r][k=j]); stores into
// fragment-major Upack[v][ks=k>>5][g4=(k>>3)&3][col][e=k&7], 65536 ush/VQC.
__global__ void ubuild_k(const float* __restrict__ gt,
                         ushort* __restrict__ Upr, ushort* __restrict__ Upi) {
    const int lane = threadIdx.x & 63;
    const int wid  = threadIdx.x >> 6;
    const int wg   = blockIdx.x * 4 + wid;     // 0..1023
    const int v    = wg >> 8;                  // 0..3
    const int j    = wg & 255;                 // basis column = k index

    float ar[4], ai[4];
#pragma unroll
    for (int r = 0; r < 4; ++r) {
        ar[r] = ((lane * 4 + r) == j) ? 1.0f : 0.0f;
        ai[r] = 0.0f;
    }

#pragma unroll
    for (int l = 0; l < 4; ++l) {
        const float* gl = gt + ((v * 4 + l) * 8) * 8;
#pragma unroll
        for (int q = 0; q < 8; ++q) {
            const float* g = gl + q * 8;
            const float g00r = g[0], g00i = g[1], g01r = g[2], g01i = g[3];
            const float g10r = g[4], g10i = g[5], g11r = g[6], g11i = g[7];
            const int b = 7 - q;
            if (b >= 2) {
                const int xm    = 1 << (b - 2);
                const int mybit = (lane >> (b - 2)) & 1;
                const float cAr = mybit ? g11r : g00r;
                const float cAi = mybit ? g11i : g00i;
                const float cBr = mybit ? g10r : g01r;
                const float cBi = mybit ? g10i : g01i;
#pragma unroll
                for (int r = 0; r < 4; ++r) {
                    const float oR = __shfl_xor(ar[r], xm, 64);
                    const float oI = __shfl_xor(ai[r], xm, 64);
                    const float nR = cAr * ar[r] - cAi * ai[r] + cBr * oR - cBi * oI;
                    const float nI = cAr * ai[r] + cAi * ar[r] + cBr * oI + cBi * oR;
                    ar[r] = nR; ai[r] = nI;
                }
            } else {
                const int step = 1 << b;
#pragma unroll
                for (int r0 = 0; r0 < 4; ++r0) {
                    if ((r0 & step) == 0) {
                        const int r1 = r0 | step;
                        const float a0r = ar[r0], a0i = ai[r0];
                        const float a1r = ar[r1], a1i = ai[r1];
                        ar[r0] = g00r * a0r - g00i * a0i + g01r * a1r - g01i * a1i;
                        ai[r0] = g00r * a0i + g00i * a0r + g01r * a1i + g01i * a1r;
                        ar[r1] = g10r * a0r - g10i * a0i + g11r * a1r - g11i * a1i;
                        ai[r1] = g10r * a0i + g10i * a0r + g11r * a1i + g11i * a1r;
                    }
                }
            }
        }
        const int roff = l + 1;
#pragma unroll
        for (int q = 0; q < 8; ++q) {
            const int t  = (q + roff) & 7;
            const int bc = 7 - q;
            const int bt = 7 - t;
            if (bt >= 2) {
                const int xm = 1 << (bt - 2);
                if (bc >= 2) {
                    const int cbit = (lane >> (bc - 2)) & 1;
#pragma unroll
                    for (int r = 0; r < 4; ++r) {
                        const float oR = __shfl_xor(ar[r], xm, 64);
                        const float oI = __shfl_xor(ai[r], xm, 64);
                        ar[r] = cbit ? oR : ar[r];
                        ai[r] = cbit ? oI : ai[r];
                    }
                } else {
#pragma unroll
                    for (int r = 0; r < 4; ++r) {
                        if ((r >> bc) & 1) {
                            ar[r] = __shfl_xor(ar[r], xm, 64);
                            ai[r] = __shfl_xor(ai[r], xm, 64);
                        }
                    }
                }
            } else {
                const int step = 1 << bt;
                if (bc >= 2) {
                    const int cbit = (lane >> (bc - 2)) & 1;
#pragma unroll
                    for (int r0 = 0; r0 < 4; ++r0) {
                        if (((r0 >> bt) & 1) == 0) {
                            const int r1 = r0 | step;
                            const float t0r = cbit ? ar[r1] : ar[r0];
                            const float t0i = cbit ? ai[r1] : ai[r0];
                            const float t1r = cbit ? ar[r0] : ar[r1];
                            const float t1i = cbit ? ai[r0] : ai[r1];
                            ar[r0] = t0r; ai[r0] = t0i;
                            ar[r1] = t1r; ai[r1] = t1i;
                        }
                    }
                } else {
#pragma unroll
                    for (int r0 = 0; r0 < 4; ++r0) {
                        if (((r0 >> bc) & 1) == 1 && ((r0 >> bt) & 1) == 0) {
                            const int r1 = r0 | step;
                            float tr = ar[r0]; ar[r0] = ar[r1]; ar[r1] = tr;
                            float ti = ai[r0]; ai[r0] = ai[r1]; ai[r1] = ti;
                        }
                    }
                }
            }
        }
    }

    // fragment-major store: Upack[v][ks][g4p][col][e], k = j
    const int ks  = j >> 5;
    const int g4p = (j >> 3) & 3;
    const int e   = j & 7;
    ushort* ur = Upr + (size_t)v * 65536 + ((ks * 4 + g4p) * 256) * 8 + e;
    ushort* ui = Upi + (size_t)v * 65536 + ((ks * 4 + g4p) * 256) * 8 + e;
#pragma unroll
    for (int r = 0; r < 4; ++r) {
        const int col = lane * 4 + r;
        ur[col * 8] = f2bf(ar[r]);
        ui[col * 8] = f2bf(ai[r]);
    }
}

// ---------------- fused main kernel ---------------------------------------
// 512 blocks x 512 threads; block owns 64 batch rows through all 4 VQCs.
// Wave w (0..7) owns 32 output cols (cols w*32..w*32+31), re AND im.
__global__ __launch_bounds__(512, 3)
void vqc_mfma_k(const float* __restrict__ xg,
                const ushort* __restrict__ Upr, const ushort* __restrict__ Upi,
                float* __restrict__ out) {
    __shared__ ushort s_lds[64 * 256];        // 32 KB, XOR-swizzled bf16
    __shared__ float  ex_part[8][64][9];      // 18 KB (pad 9 breaks stride-8)
    __shared__ float  x_lds[64][8];           // 2 KB

    const int tid  = threadIdx.x;
    const int lane = tid & 63;
    const int w    = tid >> 6;       // col group: cols w*32 .. w*32+31
    const int l15  = lane & 15;
    const int g4   = lane >> 4;
    const int rowbase = blockIdx.x * 64;

    // butterfly signs for lane bits 0..3
    const float sg0 = (lane & 1) ? -1.f : 1.f;
    const float sg1 = (lane & 2) ? -1.f : 1.f;
    const float sg2 = (lane & 4) ? -1.f : 1.f;
    const float sg3 = (lane & 8) ? -1.f : 1.f;

    // initial x into LDS (512 floats, one per thread)
    ((float*)x_lds)[tid] = xg[(size_t)rowbase * 8 + tid];
    __syncthreads();

    const int srow = tid >> 3;     // s-build: 8 threads per row
    const int sc   = tid & 7;      // 32-amp chunk (amp bits 7,6,5 = qubits 0,1,2)

    for (int v = 0; v < 4; ++v) {
        // ---- (a) build s[row][k] = prod_b f_b(k_b), bf16 swizzled ----
        {
            float hc[8], hs[8];
#pragma unroll
            for (int q = 0; q < 8; ++q) {
                float h = 0.5f * x_lds[srow][q];
                hs[q] = __sinf(h); hc[q] = __cosf(h);
            }
            float arr[32];
            arr[0] = (((sc >> 2) & 1) ? hs[0] : hc[0])
                   * (((sc >> 1) & 1) ? hs[1] : hc[1])
                   * (((sc     ) & 1) ? hs[2] : hc[2]);
#define LVL(LEN, FC, FS)                                            \
            _Pragma("unroll")                                       \
            for (int m = (LEN) - 1; m >= 0; --m) {                  \
                arr[2*m+1] = arr[m] * (FS);                         \
                arr[2*m]   = arr[m] * (FC);                         \
            }
            LVL(1,  hc[3], hs[3])   // amp bit4  (q3)
            LVL(2,  hc[4], hs[4])   // bit3      (q4)
            LVL(4,  hc[5], hs[5])   // bit2      (q5)
            LVL(8,  hc[6], hs[6])   // bit1      (q6)
            LVL(16, hc[7], hs[7])   // bit0      (q7)
#undef LVL
            char* sb = (char*)s_lds + srow * 512;
            const int swz = (srow & 7) << 4;
#pragma unroll
            for (int j = 0; j < 4; ++j) {
                uint4 wv;
                wv.x = pack2(arr[j*8+0], arr[j*8+1]);
                wv.y = pack2(arr[j*8+2], arr[j*8+3]);
                wv.z = pack2(arr[j*8+4], arr[j*8+5]);
                wv.w = pack2(arr[j*8+6], arr[j*8+7]);
                *(uint4*)(sb + ((sc * 64 + j * 16) ^ swz)) = wv;
            }
        }
        __syncthreads();

        // ---- (b) GEMM: per wave, Y(re,im)[64 rows x 32 cols] = s @ U^T ----
        // B-frags fragment-major; rolling 1-ks-ahead prefetch in registers.
        const ushort* Ur = Upr + (size_t)v * 65536;
        const ushort* Ui = Upi + (size_t)v * 65536;
        const int col0 = w * 32 + l15;         // cb = 0
        const int col1 = w * 32 + 16 + l15;    // cb = 1
        f32x4 accr[4][2], acci[4][2];
#pragma unroll
        for (int rb = 0; rb < 4; ++rb)
#pragma unroll
            for (int cb = 0; cb < 2; ++cb) {
                accr[rb][cb] = (f32x4){0.f, 0.f, 0.f, 0.f};
                acci[rb][cb] = (f32x4){0.f, 0.f, 0.f, 0.f};
            }

#define LOADB(KS, B0R, B0I, B1R, B1I) do {                          \
            const int _o0 = (((KS) * 4 + g4) * 256 + col0) * 8;     \
            const int _o1 = (((KS) * 4 + g4) * 256 + col1) * 8;     \
            B0R = *(const bf16x8*)(Ur + _o0);                       \
            B0I = *(const bf16x8*)(Ui + _o0);                       \
            B1R = *(const bf16x8*)(Ur + _o1);                       \
            B1I = *(const bf16x8*)(Ui + _o1);                       \
        } while (0)

        bf16x8 cb0r, cb0i, cb1r, cb1i;
        LOADB(0, cb0r, cb0i, cb1r, cb1i);
#pragma unroll
        for (int ks = 0; ks < 8; ++ks) {
            bf16x8 nb0r, nb0i, nb1r, nb1i;
            if (ks < 7) LOADB(ks + 1, nb0r, nb0i, nb1r, nb1i);
            bf16x8 afr[4];
#pragma unroll
            for (int rb = 0; rb < 4; ++rb) {
                const int row = rb * 16 + l15;
                const int off = row * 512 + (((ks * 64) + (g4 << 4)) ^ ((row & 7) << 4));
                afr[rb] = *(const bf16x8*)((const char*)s_lds + off);
            }
#pragma unroll
            for (int rb = 0; rb < 4; ++rb) {
                accr[rb][0] = __builtin_amdgcn_mfma_f32_16x16x32_bf16(
                    afr[rb], cb0r, accr[rb][0], 0, 0, 0);
                acci[rb][0] = __builtin_amdgcn_mfma_f32_16x16x32_bf16(
                    afr[rb], cb0i, acci[rb][0], 0, 0, 0);
                accr[rb][1] = __builtin_amdgcn_mfma_f32_16x16x32_bf16(
                    afr[rb], cb1r, accr[rb][1], 0, 0, 0);
                acci[rb][1] = __builtin_amdgcn_mfma_f32_16x16x32_bf16(
                    afr[rb], cb1i, acci[rb][1], 0, 0, 0);
            }
            if (ks < 7) { cb0r = nb0r; cb0i = nb0i; cb1r = nb1r; cb1i = nb1i; }
        }
#undef LOADB

        // ---- (c) p = |Y|^2; in-thread cb combine + carried signed butterfly
        // col bits: [3:0]=l15, [4]=cb, [7:5]=w.  qubit q <-> col bit 7-q.
#pragma unroll
        for (int rb = 0; rb < 4; ++rb) {
#pragma unroll
            for (int r = 0; r < 4; ++r) {
                const float p0 = accr[rb][0][r]*accr[rb][0][r] + acci[rb][0][r]*acci[rb][0][r];
                const float p1 = accr[rb][1][r]*accr[rb][1][r] + acci[rb][1][r]*acci[rb][1][r];
                float T0 = p0 + p1;      // total (feeds q0..q2 via w-signs, and diffs)
                float T1 = p0 - p1;      // signed cb -> col bit4 -> q3
                float d0, d1, d2, d3, pt;
                // step0 (mask1, col bit0 -> q7)
                pt = __shfl_xor(T0, 1, 64); d0 = sg0 * (T0 - pt); T0 += pt;
                pt = __shfl_xor(T1, 1, 64); T1 += pt;
                // step1 (mask2 -> q6)
                pt = __shfl_xor(T0, 2, 64); d1 = sg1 * (T0 - pt); T0 += pt;
                pt = __shfl_xor(T1, 2, 64); T1 += pt;
                pt = __shfl_xor(d0, 2, 64); d0 += pt;
                // step2 (mask4 -> q5)
                pt = __shfl_xor(T0, 4, 64); d2 = sg2 * (T0 - pt); T0 += pt;
                pt = __shfl_xor(T1, 4, 64); T1 += pt;
                pt = __shfl_xor(d0, 4, 64); d0 += pt;
                pt = __shfl_xor(d1, 4, 64); d1 += pt;
                // step3 (mask8 -> q4)
                pt = __shfl_xor(T0, 8, 64); d3 = sg3 * (T0 - pt); T0 += pt;
                pt = __shfl_xor(T1, 8, 64); T1 += pt;
                pt = __shfl_xor(d0, 8, 64); d0 += pt;
                pt = __shfl_xor(d1, 8, 64); d1 += pt;
                pt = __shfl_xor(d2, 8, 64); d2 += pt;
                if (l15 == 0) {
                    const int row = rb * 16 + g4 * 4 + r;
                    float* e = &ex_part[w][row][0];
                    e[0] = T0; e[1] = T0; e[2] = T0; e[3] = T1;
                    e[4] = d3; e[5] = d2; e[6] = d1; e[7] = d0;
                }
            }
        }
        __syncthreads();

        // ---- (d) combine col-groups: q0 sign by w bit2, q1 by w bit1, q2 by w bit0
        {
            const int row = tid >> 3, q = tid & 7;
            const bool b2 = (q == 0), b1 = (q == 1), b0 = (q == 2);
            float acc = 0.f;
#pragma unroll
            for (int g = 0; g < 8; ++g) {
                const float e = ex_part[g][row][q];
                const bool neg = (b2 && (g & 4)) || (b1 && (g & 2)) || (b0 && (g & 1));
                acc += neg ? -e : e;
            }
            x_lds[row][q] = acc;
        }
        __syncthreads();
    }

    // output = H[:,4] * float(pi - eps_f32)
    const float MULT = 3.14159253589793f;
    if (tid < 64) out[rowbase + tid] = x_lds[tid][4] * MULT;
}

// ---------------- launcher ------------------------------------------------
extern "C" void kernel_launch(void* const* d_in, const int* in_sizes, int n_in,
                              void* d_out, int out_size, void* d_ws, size_t ws_size,
                              hipStream_t stream) {
    const float* x     = (const float*)d_in[0];   // (32768, 8) fp32
    const float* theta = (const float*)d_in[1];   // (4, 4, 8, 3) fp32
    float* out = (float*)d_out;                   // (32768,) fp32

    char*   ws  = (char*)d_ws;
    float*  gt  = (float*)ws;                         // 4 KB
    ushort* Upr = (ushort*)(ws + 4096);               // 512 KB fragment-major
    ushort* Upi = (ushort*)(ws + 4096 + 524288);      // 512 KB

    gate_table_k<<<1, 128, 0, stream>>>(theta, gt);
    ubuild_k<<<256, 256, 0, stream>>>(gt, Upr, Upi);
    vqc_mfma_k<<<512, 512, 0, stream>>>(x, Upr, Upi, out);
}

// Round 9
// 126.176 us; speedup vs baseline: 1.3847x; 1.3847x over previous
//
#include <hip/hip_runtime.h>

// SingleVQC via MFMA. R9 vs R7 (best, 103us): the 14-shfl/slot butterfly
// reduction (224 ds_swizzle + ~450 VALU per wave per VQC) is replaced by an
// MFMA reduction: (b) swaps operand roles -> C = Y^T (cols=batchrows), so
// each lane's C rows are state-cols; (c) squares to p, splits p into
// interleaved (hi,lo) bf16 pairs forming a K=32 B-fragment directly, and one
// 16x16x32 MFMA vs a +-1 sign matrix (built in-regs from lane bits) yields
// all 8 expvals. Memory access pattern of (b) is byte-identical to R7.
// Register budget kept <= 128 total (R8 lesson: occupancy halves past 128).

typedef __attribute__((ext_vector_type(8))) short  bf16x8;
typedef __attribute__((ext_vector_type(4))) float  f32x4;

__device__ __forceinline__ ushort f2bf(float f) {
    unsigned u = __builtin_bit_cast(unsigned, f);
    u += 0x7fffu + ((u >> 16) & 1u);          // RNE
    return (ushort)(u >> 16);
}
__device__ __forceinline__ float bf2f(ushort h) {
    unsigned u = ((unsigned)h) << 16;
    return __builtin_bit_cast(float, u);
}
__device__ __forceinline__ unsigned pack2(float a, float b) {
    return ((unsigned)f2bf(b) << 16) | (unsigned)f2bf(a);
}

// ---------------- gate-table prologue (unchanged, verified) ---------------
__global__ void gate_table_k(const float* __restrict__ theta,
                             float* __restrict__ gt) {
    int idx = blockIdx.x * blockDim.x + threadIdx.x;
    if (idx >= 128) return;
    float phi = theta[idx * 3 + 0];
    float th  = theta[idx * 3 + 1];
    float om  = theta[idx * 3 + 2];
    float ct = __cosf(0.5f * th),         st = __sinf(0.5f * th);
    float ca = __cosf(0.5f * (phi - om)), sa = __sinf(0.5f * (phi - om));
    float cb = __cosf(0.5f * (phi + om)), sb = __sinf(0.5f * (phi + om));
    float* g = gt + idx * 8;
    g[0] =  cb * ct;  g[1] = -sb * ct;
    g[2] = -ca * st;  g[3] = -sa * st;
    g[4] =  ca * st;  g[5] = -sa * st;
    g[6] =  cb * ct;  g[7] =  sb * ct;
}

// ---------------- U-build (unchanged, verified): fragment-major store -----
__global__ void ubuild_k(const float* __restrict__ gt,
                         ushort* __restrict__ Upr, ushort* __restrict__ Upi) {
    const int lane = threadIdx.x & 63;
    const int wid  = threadIdx.x >> 6;
    const int wg   = blockIdx.x * 4 + wid;     // 0..1023
    const int v    = wg >> 8;                  // 0..3
    const int j    = wg & 255;                 // basis column = k index

    float ar[4], ai[4];
#pragma unroll
    for (int r = 0; r < 4; ++r) {
        ar[r] = ((lane * 4 + r) == j) ? 1.0f : 0.0f;
        ai[r] = 0.0f;
    }

#pragma unroll
    for (int l = 0; l < 4; ++l) {
        const float* gl = gt + ((v * 4 + l) * 8) * 8;
#pragma unroll
        for (int q = 0; q < 8; ++q) {
            const float* g = gl + q * 8;
            const float g00r = g[0], g00i = g[1], g01r = g[2], g01i = g[3];
            const float g10r = g[4], g10i = g[5], g11r = g[6], g11i = g[7];
            const int b = 7 - q;
            if (b >= 2) {
                const int xm    = 1 << (b - 2);
                const int mybit = (lane >> (b - 2)) & 1;
                const float cAr = mybit ? g11r : g00r;
                const float cAi = mybit ? g11i : g00i;
                const float cBr = mybit ? g10r : g01r;
                const float cBi = mybit ? g10i : g01i;
#pragma unroll
                for (int r = 0; r < 4; ++r) {
                    const float oR = __shfl_xor(ar[r], xm, 64);
                    const float oI = __shfl_xor(ai[r], xm, 64);
                    const float nR = cAr * ar[r] - cAi * ai[r] + cBr * oR - cBi * oI;
                    const float nI = cAr * ai[r] + cAi * ar[r] + cBr * oI + cBi * oR;
                    ar[r] = nR; ai[r] = nI;
                }
            } else {
                const int step = 1 << b;
#pragma unroll
                for (int r0 = 0; r0 < 4; ++r0) {
                    if ((r0 & step) == 0) {
                        const int r1 = r0 | step;
                        const float a0r = ar[r0], a0i = ai[r0];
                        const float a1r = ar[r1], a1i = ai[r1];
                        ar[r0] = g00r * a0r - g00i * a0i + g01r * a1r - g01i * a1i;
                        ai[r0] = g00r * a0i + g00i * a0r + g01r * a1i + g01i * a1r;
                        ar[r1] = g10r * a0r - g10i * a0i + g11r * a1r - g11i * a1i;
                        ai[r1] = g10r * a0i + g10i * a0r + g11r * a1i + g11i * a1r;
                    }
                }
            }
        }
        const int roff = l + 1;
#pragma unroll
        for (int q = 0; q < 8; ++q) {
            const int t  = (q + roff) & 7;
            const int bc = 7 - q;
            const int bt = 7 - t;
            if (bt >= 2) {
                const int xm = 1 << (bt - 2);
                if (bc >= 2) {
                    const int cbit = (lane >> (bc - 2)) & 1;
#pragma unroll
                    for (int r = 0; r < 4; ++r) {
                        const float oR = __shfl_xor(ar[r], xm, 64);
                        const float oI = __shfl_xor(ai[r], xm, 64);
                        ar[r] = cbit ? oR : ar[r];
                        ai[r] = cbit ? oI : ai[r];
                    }
                } else {
#pragma unroll
                    for (int r = 0; r < 4; ++r) {
                        if ((r >> bc) & 1) {
                            ar[r] = __shfl_xor(ar[r], xm, 64);
                            ai[r] = __shfl_xor(ai[r], xm, 64);
                        }
                    }
                }
            } else {
                const int step = 1 << bt;
                if (bc >= 2) {
                    const int cbit = (lane >> (bc - 2)) & 1;
#pragma unroll
                    for (int r0 = 0; r0 < 4; ++r0) {
                        if (((r0 >> bt) & 1) == 0) {
                            const int r1 = r0 | step;
                            const float t0r = cbit ? ar[r1] : ar[r0];
                            const float t0i = cbit ? ai[r1] : ai[r0];
                            const float t1r = cbit ? ar[r0] : ar[r1];
                            const float t1i = cbit ? ai[r0] : ai[r1];
                            ar[r0] = t0r; ai[r0] = t0i;
                            ar[r1] = t1r; ai[r1] = t1i;
                        }
                    }
                } else {
#pragma unroll
                    for (int r0 = 0; r0 < 4; ++r0) {
                        if (((r0 >> bc) & 1) == 1 && ((r0 >> bt) & 1) == 0) {
                            const int r1 = r0 | step;
                            float tr = ar[r0]; ar[r0] = ar[r1]; ar[r1] = tr;
                            float ti = ai[r0]; ai[r0] = ai[r1]; ai[r1] = ti;
                        }
                    }
                }
            }
        }
    }

    // fragment-major store: Upack[v][ks][g4p][col][e], k = j
    const int ks  = j >> 5;
    const int g4p = (j >> 3) & 3;
    const int e   = j & 7;
    ushort* ur = Upr + (size_t)v * 65536 + ((ks * 4 + g4p) * 256) * 8 + e;
    ushort* ui = Upi + (size_t)v * 65536 + ((ks * 4 + g4p) * 256) * 8 + e;
#pragma unroll
    for (int r = 0; r < 4; ++r) {
        const int col = lane * 4 + r;
        ur[col * 8] = f2bf(ar[r]);
        ui[col * 8] = f2bf(ai[r]);
    }
}

// ---------------- fused main kernel ---------------------------------------
// 512 blocks x 512 threads; block owns 64 batch rows through all 4 VQCs.
// Wave w (0..7) owns 32 state-cols (w*32..w*32+31); C = Y^T.
__global__ __launch_bounds__(512, 4)
void vqc_mfma_k(const float* __restrict__ xg,
                const ushort* __restrict__ Upr, const ushort* __restrict__ Upi,
                float* __restrict__ out) {
    __shared__ ushort s_lds[64 * 256];        // 32 KB, XOR-swizzled bf16
    __shared__ float  ex_part[8][64][9];      // 18 KB (pad 9)
    __shared__ float  x_lds[64][8];           // 2 KB

    const int tid  = threadIdx.x;
    const int lane = tid & 63;
    const int w    = tid >> 6;       // state-col group: cols w*32 .. w*32+31
    const int l15  = lane & 15;
    const int g4   = lane >> 4;
    const int rowbase = blockIdx.x * 64;

    // ---- sign-matrix A fragments (built once; 8 VGPRs) ----
    // A_sgn[mg]: A[q=l15][k=g4*8+e], statecol = w*32 + mg*16 + g4*4 + (e>>1);
    // value = +-1 (bf16) by bit (7-q) of statecol for q<8, else 0.
    bf16x8 asgn0, asgn1;
    {
        const int q = l15;
#pragma unroll
        for (int mg = 0; mg < 2; ++mg) {
            unsigned wd[4];
#pragma unroll
            for (int p2 = 0; p2 < 4; ++p2) {    // p2 = e>>1
                const int scol = w * 32 + mg * 16 + g4 * 4 + p2;
                ushort uv = 0;
                if (q < 8) uv = ((scol >> (7 - q)) & 1) ? 0xBF80 : 0x3F80;
                wd[p2] = ((unsigned)uv << 16) | uv;   // same sign for hi,lo slots
            }
            const uint4 u4 = {wd[0], wd[1], wd[2], wd[3]};
            if (mg == 0) asgn0 = __builtin_bit_cast(bf16x8, u4);
            else         asgn1 = __builtin_bit_cast(bf16x8, u4);
        }
    }

    // initial x into LDS (512 floats, one per thread)
    ((float*)x_lds)[tid] = xg[(size_t)rowbase * 8 + tid];
    __syncthreads();

    const int srow = tid >> 3;     // s-build: 8 threads per row
    const int sc   = tid & 7;      // 32-amp chunk (amp bits 7,6,5 = qubits 0,1,2)

    for (int v = 0; v < 4; ++v) {
        // ---- (a) build s[row][k] = prod_b f_b(k_b), bf16 swizzled ----
        {
            float hc[8], hs[8];
#pragma unroll
            for (int q = 0; q < 8; ++q) {
                float h = 0.5f * x_lds[srow][q];
                hs[q] = __sinf(h); hc[q] = __cosf(h);
            }
            float arr[32];
            arr[0] = (((sc >> 2) & 1) ? hs[0] : hc[0])
                   * (((sc >> 1) & 1) ? hs[1] : hc[1])
                   * (((sc     ) & 1) ? hs[2] : hc[2]);
#define LVL(LEN, FC, FS)                                            \
            _Pragma("unroll")                                       \
            for (int m = (LEN) - 1; m >= 0; --m) {                  \
                arr[2*m+1] = arr[m] * (FS);                         \
                arr[2*m]   = arr[m] * (FC);                         \
            }
            LVL(1,  hc[3], hs[3])   // amp bit4  (q3)
            LVL(2,  hc[4], hs[4])   // bit3      (q4)
            LVL(4,  hc[5], hs[5])   // bit2      (q5)
            LVL(8,  hc[6], hs[6])   // bit1      (q6)
            LVL(16, hc[7], hs[7])   // bit0      (q7)
#undef LVL
            char* sb = (char*)s_lds + srow * 512;
            const int swz = (srow & 7) << 4;
#pragma unroll
            for (int j = 0; j < 4; ++j) {
                uint4 wv;
                wv.x = pack2(arr[j*8+0], arr[j*8+1]);
                wv.y = pack2(arr[j*8+2], arr[j*8+3]);
                wv.z = pack2(arr[j*8+4], arr[j*8+5]);
                wv.w = pack2(arr[j*8+6], arr[j*8+7]);
                *(uint4*)(sb + ((sc * 64 + j * 16) ^ swz)) = wv;
            }
        }
        __syncthreads();

        // ---- (b) GEMM: C = Y^T per wave: 32 state-cols x 64 batch-rows ----
        // A = U fragments (same addresses as R7's B), B = s fragments (same
        // addresses as R7's A). acc[mg][ng], 64 AGPR.
        const ushort* Ur = Upr + (size_t)v * 65536;
        const ushort* Ui = Upi + (size_t)v * 65536;
        f32x4 accr[2][4], acci[2][4];
#pragma unroll
        for (int mg = 0; mg < 2; ++mg)
#pragma unroll
            for (int ng = 0; ng < 4; ++ng) {
                accr[mg][ng] = (f32x4){0.f, 0.f, 0.f, 0.f};
                acci[mg][ng] = (f32x4){0.f, 0.f, 0.f, 0.f};
            }

#pragma unroll
        for (int ks = 0; ks < 8; ++ks) {
            bf16x8 aur[2], aui[2];
#pragma unroll
            for (int mg = 0; mg < 2; ++mg) {
                const int col  = w * 32 + mg * 16 + l15;
                const int boff = ((ks * 4 + g4) * 256 + col) * 8;
                aur[mg] = *(const bf16x8*)(Ur + boff);
                aui[mg] = *(const bf16x8*)(Ui + boff);
            }
            bf16x8 bs[4];
#pragma unroll
            for (int ng = 0; ng < 4; ++ng) {
                const int row = ng * 16 + l15;
                const int off = row * 512 + (((ks * 64) + (g4 << 4)) ^ ((row & 7) << 4));
                bs[ng] = *(const bf16x8*)((const char*)s_lds + off);
            }
#pragma unroll
            for (int mg = 0; mg < 2; ++mg)
#pragma unroll
                for (int ng = 0; ng < 4; ++ng) {
                    accr[mg][ng] = __builtin_amdgcn_mfma_f32_16x16x32_bf16(
                        aur[mg], bs[ng], accr[mg][ng], 0, 0, 0);
                    acci[mg][ng] = __builtin_amdgcn_mfma_f32_16x16x32_bf16(
                        aui[mg], bs[ng], acci[mg][ng], 0, 0, 0);
                }
        }

        // ---- (c) p = |Y|^2 -> (hi,lo) bf16 interleaved B-frag -> one MFMA
        // vs sign matrix per (mg): E[q][batchrow] accumulated per ng.
#pragma unroll
        for (int ng = 0; ng < 4; ++ng) {
            f32x4 E = (f32x4){0.f, 0.f, 0.f, 0.f};
#pragma unroll
            for (int mg = 0; mg < 2; ++mg) {
                unsigned wd[4];
#pragma unroll
                for (int r = 0; r < 4; ++r) {
                    const float pr = accr[mg][ng][r] * accr[mg][ng][r]
                                   + acci[mg][ng][r] * acci[mg][ng][r];
                    const ushort hi = f2bf(pr);
                    const ushort lo = f2bf(pr - bf2f(hi));
                    wd[r] = ((unsigned)lo << 16) | hi;
                }
                const uint4 u4 = {wd[0], wd[1], wd[2], wd[3]};
                const bf16x8 pb = __builtin_bit_cast(bf16x8, u4);
                E = __builtin_amdgcn_mfma_f32_16x16x32_bf16(
                    (mg == 0) ? asgn0 : asgn1, pb, E, 0, 0, 0);
            }
            if (g4 < 2) {
                const int row = ng * 16 + l15;   // batch row
#pragma unroll
                for (int r = 0; r < 4; ++r)
                    ex_part[w][row][g4 * 4 + r] = E[r];   // q = g4*4+r
            }
        }
        __syncthreads();

        // ---- (d) combine state-col groups (plain sum; signs in A_sgn) ----
        {
            const int row = tid >> 3, q = tid & 7;
            float acc = 0.f;
#pragma unroll
            for (int g = 0; g < 8; ++g) acc += ex_part[g][row][q];
            x_lds[row][q] = acc;
        }
        __syncthreads();
    }

    // output = H[:,4] * float(pi - eps_f32)
    const float MULT = 3.14159253589793f;
    if (tid < 64) out[rowbase + tid] = x_lds[tid][4] * MULT;
}

// ---------------- launcher ------------------------------------------------
extern "C" void kernel_launch(void* const* d_in, const int* in_sizes, int n_in,
                              void* d_out, int out_size, void* d_ws, size_t ws_size,
                              hipStream_t stream) {
    const float* x     = (const float*)d_in[0];   // (32768, 8) fp32
    const float* theta = (const float*)d_in[1];   // (4, 4, 8, 3) fp32
    float* out = (float*)d_out;                   // (32768,) fp32

    char*   ws  = (char*)d_ws;
    float*  gt  = (float*)ws;                         // 4 KB
    ushort* Upr = (ushort*)(ws + 4096);               // 512 KB fragment-major
    ushort* Upi = (ushort*)(ws + 4096 + 524288);      // 512 KB

    gate_table_k<<<1, 128, 0, stream>>>(theta, gt);
    ubuild_k<<<256, 256, 0, stream>>>(gt, Upr, Upi);
    vqc_mfma_k<<<512, 512, 0, stream>>>(x, Upr, Upi, out);
}

// Round 10
// 116.135 us; speedup vs baseline: 1.5044x; 1.0865x over previous
//
#include <hip/hip_runtime.h>

// SingleVQC via MFMA. R10 vs R9 (best, 66us steady): occupancy was the limit
// (12.5 waves/CU; 64 VGPR + 64 AGPR = 128 = allocation cliff). The mg
// (col-group) loop is hoisted outermost in (b)+(c): per mg the GEMM needs only
// acc[4]x2 = 32 AGPR, reused across mg; reduction accumulator E[4] (16 regs)
// carries across. Total ~100 regs -> ~20 waves/CU. Arithmetic order identical
// to R9 (absmax must stay 0.046875 exactly).

typedef __attribute__((ext_vector_type(8))) short  bf16x8;
typedef __attribute__((ext_vector_type(4))) float  f32x4;

__device__ __forceinline__ ushort f2bf(float f) {
    unsigned u = __builtin_bit_cast(unsigned, f);
    u += 0x7fffu + ((u >> 16) & 1u);          // RNE
    return (ushort)(u >> 16);
}
__device__ __forceinline__ float bf2f(ushort h) {
    unsigned u = ((unsigned)h) << 16;
    return __builtin_bit_cast(float, u);
}
__device__ __forceinline__ unsigned pack2(float a, float b) {
    return ((unsigned)f2bf(b) << 16) | (unsigned)f2bf(a);
}

// ---------------- gate-table prologue (unchanged, verified) ---------------
__global__ void gate_table_k(const float* __restrict__ theta,
                             float* __restrict__ gt) {
    int idx = blockIdx.x * blockDim.x + threadIdx.x;
    if (idx >= 128) return;
    float phi = theta[idx * 3 + 0];
    float th  = theta[idx * 3 + 1];
    float om  = theta[idx * 3 + 2];
    float ct = __cosf(0.5f * th),         st = __sinf(0.5f * th);
    float ca = __cosf(0.5f * (phi - om)), sa = __sinf(0.5f * (phi - om));
    float cb = __cosf(0.5f * (phi + om)), sb = __sinf(0.5f * (phi + om));
    float* g = gt + idx * 8;
    g[0] =  cb * ct;  g[1] = -sb * ct;
    g[2] = -ca * st;  g[3] = -sa * st;
    g[4] =  ca * st;  g[5] = -sa * st;
    g[6] =  cb * ct;  g[7] =  sb * ct;
}

// ---------------- U-build (unchanged, verified): fragment-major store -----
__global__ void ubuild_k(const float* __restrict__ gt,
                         ushort* __restrict__ Upr, ushort* __restrict__ Upi) {
    const int lane = threadIdx.x & 63;
    const int wid  = threadIdx.x >> 6;
    const int wg   = blockIdx.x * 4 + wid;     // 0..1023
    const int v    = wg >> 8;                  // 0..3
    const int j    = wg & 255;                 // basis column = k index

    float ar[4], ai[4];
#pragma unroll
    for (int r = 0; r < 4; ++r) {
        ar[r] = ((lane * 4 + r) == j) ? 1.0f : 0.0f;
        ai[r] = 0.0f;
    }

#pragma unroll
    for (int l = 0; l < 4; ++l) {
        const float* gl = gt + ((v * 4 + l) * 8) * 8;
#pragma unroll
        for (int q = 0; q < 8; ++q) {
            const float* g = gl + q * 8;
            const float g00r = g[0], g00i = g[1], g01r = g[2], g01i = g[3];
            const float g10r = g[4], g10i = g[5], g11r = g[6], g11i = g[7];
            const int b = 7 - q;
            if (b >= 2) {
                const int xm    = 1 << (b - 2);
                const int mybit = (lane >> (b - 2)) & 1;
                const float cAr = mybit ? g11r : g00r;
                const float cAi = mybit ? g11i : g00i;
                const float cBr = mybit ? g10r : g01r;
                const float cBi = mybit ? g10i : g01i;
#pragma unroll
                for (int r = 0; r < 4; ++r) {
                    const float oR = __shfl_xor(ar[r], xm, 64);
                    const float oI = __shfl_xor(ai[r], xm, 64);
                    const float nR = cAr * ar[r] - cAi * ai[r] + cBr * oR - cBi * oI;
                    const float nI = cAr * ai[r] + cAi * ar[r] + cBr * oI + cBi * oR;
                    ar[r] = nR; ai[r] = nI;
                }
            } else {
                const int step = 1 << b;
#pragma unroll
                for (int r0 = 0; r0 < 4; ++r0) {
                    if ((r0 & step) == 0) {
                        const int r1 = r0 | step;
                        const float a0r = ar[r0], a0i = ai[r0];
                        const float a1r = ar[r1], a1i = ai[r1];
                        ar[r0] = g00r * a0r - g00i * a0i + g01r * a1r - g01i * a1i;
                        ai[r0] = g00r * a0i + g00i * a0r + g01r * a1i + g01i * a1r;
                        ar[r1] = g10r * a0r - g10i * a0i + g11r * a1r - g11i * a1i;
                        ai[r1] = g10r * a0i + g10i * a0r + g11r * a1i + g11i * a1r;
                    }
                }
            }
        }
        const int roff = l + 1;
#pragma unroll
        for (int q = 0; q < 8; ++q) {
            const int t  = (q + roff) & 7;
            const int bc = 7 - q;
            const int bt = 7 - t;
            if (bt >= 2) {
                const int xm = 1 << (bt - 2);
                if (bc >= 2) {
                    const int cbit = (lane >> (bc - 2)) & 1;
#pragma unroll
                    for (int r = 0; r < 4; ++r) {
                        const float oR = __shfl_xor(ar[r], xm, 64);
                        const float oI = __shfl_xor(ai[r], xm, 64);
                        ar[r] = cbit ? oR : ar[r];
                        ai[r] = cbit ? oI : ai[r];
                    }
                } else {
#pragma unroll
                    for (int r = 0; r < 4; ++r) {
                        if ((r >> bc) & 1) {
                            ar[r] = __shfl_xor(ar[r], xm, 64);
                            ai[r] = __shfl_xor(ai[r], xm, 64);
                        }
                    }
                }
            } else {
                const int step = 1 << bt;
                if (bc >= 2) {
                    const int cbit = (lane >> (bc - 2)) & 1;
#pragma unroll
                    for (int r0 = 0; r0 < 4; ++r0) {
                        if (((r0 >> bt) & 1) == 0) {
                            const int r1 = r0 | step;
                            const float t0r = cbit ? ar[r1] : ar[r0];
                            const float t0i = cbit ? ai[r1] : ai[r0];
                            const float t1r = cbit ? ar[r0] : ar[r1];
                            const float t1i = cbit ? ai[r0] : ai[r1];
                            ar[r0] = t0r; ai[r0] = t0i;
                            ar[r1] = t1r; ai[r1] = t1i;
                        }
                    }
                } else {
#pragma unroll
                    for (int r0 = 0; r0 < 4; ++r0) {
                        if (((r0 >> bc) & 1) == 1 && ((r0 >> bt) & 1) == 0) {
                            const int r1 = r0 | step;
                            float tr = ar[r0]; ar[r0] = ar[r1]; ar[r1] = tr;
                            float ti = ai[r0]; ai[r0] = ai[r1]; ai[r1] = ti;
                        }
                    }
                }
            }
        }
    }

    // fragment-major store: Upack[v][ks][g4p][col][e], k = j
    const int ks  = j >> 5;
    const int g4p = (j >> 3) & 3;
    const int e   = j & 7;
    ushort* ur = Upr + (size_t)v * 65536 + ((ks * 4 + g4p) * 256) * 8 + e;
    ushort* ui = Upi + (size_t)v * 65536 + ((ks * 4 + g4p) * 256) * 8 + e;
#pragma unroll
    for (int r = 0; r < 4; ++r) {
        const int col = lane * 4 + r;
        ur[col * 8] = f2bf(ar[r]);
        ui[col * 8] = f2bf(ai[r]);
    }
}

// ---------------- fused main kernel ---------------------------------------
// 512 blocks x 512 threads; block owns 64 batch rows through all 4 VQCs.
// Wave w (0..7) owns 32 state-cols, processed as two 16-col passes (mg).
__global__ __launch_bounds__(512, 4)
void vqc_mfma_k(const float* __restrict__ xg,
                const ushort* __restrict__ Upr, const ushort* __restrict__ Upi,
                float* __restrict__ out) {
    __shared__ ushort s_lds[64 * 256];        // 32 KB, XOR-swizzled bf16
    __shared__ float  ex_part[8][64][9];      // 18 KB (pad 9)
    __shared__ float  x_lds[64][8];           // 2 KB

    const int tid  = threadIdx.x;
    const int lane = tid & 63;
    const int w    = tid >> 6;       // state-col group: cols w*32 .. w*32+31
    const int l15  = lane & 15;
    const int g4   = lane >> 4;
    const int rowbase = blockIdx.x * 64;

    // ---- sign-matrix A fragments (built once; 8 VGPRs) ----
    // A_sgn[mg]: A[q=l15][k=g4*8+e], statecol = w*32 + mg*16 + g4*4 + (e>>1);
    // value = +-1 (bf16) by bit (7-q) of statecol for q<8, else 0.
    bf16x8 asgn0, asgn1;
    {
        const int q = l15;
#pragma unroll
        for (int mg = 0; mg < 2; ++mg) {
            unsigned wd[4];
#pragma unroll
            for (int p2 = 0; p2 < 4; ++p2) {    // p2 = e>>1
                const int scol = w * 32 + mg * 16 + g4 * 4 + p2;
                ushort uv = 0;
                if (q < 8) uv = ((scol >> (7 - q)) & 1) ? 0xBF80 : 0x3F80;
                wd[p2] = ((unsigned)uv << 16) | uv;   // same sign for hi,lo slots
            }
            const uint4 u4 = {wd[0], wd[1], wd[2], wd[3]};
            if (mg == 0) asgn0 = __builtin_bit_cast(bf16x8, u4);
            else         asgn1 = __builtin_bit_cast(bf16x8, u4);
        }
    }

    // initial x into LDS (512 floats, one per thread)
    ((float*)x_lds)[tid] = xg[(size_t)rowbase * 8 + tid];
    __syncthreads();

    const int srow = tid >> 3;     // s-build: 8 threads per row
    const int sc   = tid & 7;      // 32-amp chunk (amp bits 7,6,5 = qubits 0,1,2)

    for (int v = 0; v < 4; ++v) {
        // ---- (a) build s[row][k] = prod_b f_b(k_b), bf16 swizzled ----
        {
            float hc[8], hs[8];
#pragma unroll
            for (int q = 0; q < 8; ++q) {
                float h = 0.5f * x_lds[srow][q];
                hs[q] = __sinf(h); hc[q] = __cosf(h);
            }
            float arr[32];
            arr[0] = (((sc >> 2) & 1) ? hs[0] : hc[0])
                   * (((sc >> 1) & 1) ? hs[1] : hc[1])
                   * (((sc     ) & 1) ? hs[2] : hc[2]);
#define LVL(LEN, FC, FS)                                            \
            _Pragma("unroll")                                       \
            for (int m = (LEN) - 1; m >= 0; --m) {                  \
                arr[2*m+1] = arr[m] * (FS);                         \
                arr[2*m]   = arr[m] * (FC);                         \
            }
            LVL(1,  hc[3], hs[3])   // amp bit4  (q3)
            LVL(2,  hc[4], hs[4])   // bit3      (q4)
            LVL(4,  hc[5], hs[5])   // bit2      (q5)
            LVL(8,  hc[6], hs[6])   // bit1      (q6)
            LVL(16, hc[7], hs[7])   // bit0      (q7)
#undef LVL
            char* sb = (char*)s_lds + srow * 512;
            const int swz = (srow & 7) << 4;
#pragma unroll
            for (int j = 0; j < 4; ++j) {
                uint4 wv;
                wv.x = pack2(arr[j*8+0], arr[j*8+1]);
                wv.y = pack2(arr[j*8+2], arr[j*8+3]);
                wv.z = pack2(arr[j*8+4], arr[j*8+5]);
                wv.w = pack2(arr[j*8+6], arr[j*8+7]);
                *(uint4*)(sb + ((sc * 64 + j * 16) ^ swz)) = wv;
            }
        }
        __syncthreads();

        // ---- (b)+(c): per mg (16 cols): GEMM (32 AGPR acc) -> p -> E ----
        const ushort* Ur = Upr + (size_t)v * 65536;
        const ushort* Ui = Upi + (size_t)v * 65536;
        f32x4 E0 = {0.f,0.f,0.f,0.f}, E1 = {0.f,0.f,0.f,0.f};
        f32x4 E2 = {0.f,0.f,0.f,0.f}, E3 = {0.f,0.f,0.f,0.f};

#pragma unroll
        for (int mg = 0; mg < 2; ++mg) {
            f32x4 accr[4], acci[4];
#pragma unroll
            for (int ng = 0; ng < 4; ++ng) {
                accr[ng] = (f32x4){0.f, 0.f, 0.f, 0.f};
                acci[ng] = (f32x4){0.f, 0.f, 0.f, 0.f};
            }
            const int col = w * 32 + mg * 16 + l15;
#pragma unroll
            for (int ks = 0; ks < 8; ++ks) {
                const int boff = ((ks * 4 + g4) * 256 + col) * 8;
                const bf16x8 aur = *(const bf16x8*)(Ur + boff);
                const bf16x8 aui = *(const bf16x8*)(Ui + boff);
                bf16x8 bs[4];
#pragma unroll
                for (int ng = 0; ng < 4; ++ng) {
                    const int row = ng * 16 + l15;
                    const int off = row * 512 + (((ks * 64) + (g4 << 4)) ^ ((row & 7) << 4));
                    bs[ng] = *(const bf16x8*)((const char*)s_lds + off);
                }
#pragma unroll
                for (int ng = 0; ng < 4; ++ng) {
                    accr[ng] = __builtin_amdgcn_mfma_f32_16x16x32_bf16(
                        aur, bs[ng], accr[ng], 0, 0, 0);
                    acci[ng] = __builtin_amdgcn_mfma_f32_16x16x32_bf16(
                        aui, bs[ng], acci[ng], 0, 0, 0);
                }
            }
            // square -> (hi,lo) bf16 packed B-frag -> reduction MFMA into E
            const bf16x8 asgn = (mg == 0) ? asgn0 : asgn1;
#pragma unroll
            for (int ng = 0; ng < 4; ++ng) {
                unsigned wd[4];
#pragma unroll
                for (int r = 0; r < 4; ++r) {
                    const float pr = accr[ng][r] * accr[ng][r]
                                   + acci[ng][r] * acci[ng][r];
                    const ushort hi = f2bf(pr);
                    const ushort lo = f2bf(pr - bf2f(hi));
                    wd[r] = ((unsigned)lo << 16) | hi;
                }
                const uint4 u4 = {wd[0], wd[1], wd[2], wd[3]};
                const bf16x8 pb = __builtin_bit_cast(bf16x8, u4);
                f32x4 Ein = (ng == 0) ? E0 : (ng == 1) ? E1 : (ng == 2) ? E2 : E3;
                const f32x4 Eout = __builtin_amdgcn_mfma_f32_16x16x32_bf16(
                    asgn, pb, Ein, 0, 0, 0);
                if (ng == 0) E0 = Eout; else if (ng == 1) E1 = Eout;
                else if (ng == 2) E2 = Eout; else E3 = Eout;
            }
        }

        // ---- write expval partials (q = g4*4+r valid for g4<2) ----
        if (g4 < 2) {
#pragma unroll
            for (int ng = 0; ng < 4; ++ng) {
                const f32x4 Ev = (ng == 0) ? E0 : (ng == 1) ? E1 : (ng == 2) ? E2 : E3;
                const int row = ng * 16 + l15;   // batch row
#pragma unroll
                for (int r = 0; r < 4; ++r)
                    ex_part[w][row][g4 * 4 + r] = Ev[r];
            }
        }
        __syncthreads();

        // ---- (d) combine state-col groups (plain sum; signs in A_sgn) ----
        {
            const int row = tid >> 3, q = tid & 7;
            float acc = 0.f;
#pragma unroll
            for (int g = 0; g < 8; ++g) acc += ex_part[g][row][q];
            x_lds[row][q] = acc;
        }
        __syncthreads();
    }

    // output = H[:,4] * float(pi - eps_f32)
    const float MULT = 3.14159253589793f;
    if (tid < 64) out[rowbase + tid] = x_lds[tid][4] * MULT;
}

// ---------------- launcher ------------------------------------------------
extern "C" void kernel_launch(void* const* d_in, const int* in_sizes, int n_in,
                              void* d_out, int out_size, void* d_ws, size_t ws_size,
                              hipStream_t stream) {
    const float* x     = (const float*)d_in[0];   // (32768, 8) fp32
    const float* theta = (const float*)d_in[1];   // (4, 4, 8, 3) fp32
    float* out = (float*)d_out;                   // (32768,) fp32

    char*   ws  = (char*)d_ws;
    float*  gt  = (float*)ws;                         // 4 KB
    ushort* Upr = (ushort*)(ws + 4096);               // 512 KB fragment-major
    ushort* Upi = (ushort*)(ws + 4096 + 524288);      // 512 KB

    gate_table_k<<<1, 128, 0, stream>>>(theta, gt);
    ubuild_k<<<256, 256, 0, stream>>>(gt, Upr, Upi);
    vqc_mfma_k<<<512, 512, 0, stream>>>(x, Upr, Upi, out);
}